// Round 17
// baseline (127.287 us; speedup 1.0000x reference)
//
#include <hip/hip_runtime.h>

#define VOCAB 10000
#define EMB   16
#define HID   32
#define BATCH 4096
#define TLEN  512

typedef _Float16 f16x2 __attribute__((ext_vector_type(2)));
typedef _Float16 f16x8 __attribute__((ext_vector_type(8)));

#define TWO_LOG2E 2.8853900817779268f   /* 2*log2(e) */

// ---------------------------------------------------------------------------
// Kernel 1: P'[v][j] = (b[j] + sum_e emb[v][e]*Wx[e][j]) * 2log2e
// ---------------------------------------------------------------------------
__global__ __launch_bounds__(256) void rnn_proj(
    const float* __restrict__ emb, const float* __restrict__ Wx,
    const float* __restrict__ bias, float* __restrict__ P)
{
    int tid = blockIdx.x * 256 + threadIdx.x;
    if (tid >= VOCAB * HID) return;
    int v = tid >> 5;
    int j = tid & 31;
    float acc = bias[j];
    const float* ev = emb + v * EMB;
#pragma unroll
    for (int e = 0; e < EMB; ++e) {
        acc = fmaf(ev[e], Wx[e * HID + j], acc);
    }
    P[tid] = acc * TWO_LOG2E;
}

// ---------------------------------------------------------------------------
// Kernel 2: dual-chain fdot2 scan. Wave = 4 batches as TWO independent
// recurrence chains (A = batches {0,1}, B = {2,3}); per lane (j, half):
// full 32-MAC dot via 16 v_dot2_f32_f16 per chain. The chains are SKEWED
// in program order so each chain's LDS write->read round-trip (~120cy) is
// covered by the OTHER chain's compute (~110cy of issue) — deterministic
// ILP instead of r16's scheduler-dependent TLP (which left 40% stall:
// both waves hit the LDS stall in phase).
// 1024 waves = 1/SIMD exactly (256 blocks x 4 waves = 1 block/CU).
// Keeps r16's proven shaves: 2log2e fold (exp2 direct), 2 accumulators,
// f16 h rows, quad unroll, int4 tokens, P prefetch, pinned weights.
// ---------------------------------------------------------------------------
__global__ __launch_bounds__(256)
__attribute__((amdgpu_waves_per_eu(1, 1)))
void rnn_scan(
    const int*   __restrict__ x,   const float* __restrict__ P,
    const float* __restrict__ Wh,  const float* __restrict__ Wd,
    const float* __restrict__ bd,  float* __restrict__ out)
{
    __shared__ _Float16 h_lds[16][HID];         // 4 waves x 4 rows x 64 B

    const int lane = threadIdx.x & 63;
    const int wave = threadIdx.x >> 6;
    const int half = lane >> 5;
    const int j    = lane & 31;
    const int w4   = (blockIdx.x * 4 + wave) * 4;   // wave's 4-batch base
    const int bA   = w4 + half;                 // chain A batch
    const int bB   = w4 + 2 + half;             // chain B batch
    const int rA   = wave * 4 + half;           // chain A LDS row
    const int rB   = wave * 4 + 2 + half;       // chain B LDS row

    // Wh column j, pre-scaled by 2log2e, as fp16 pairs (shared by chains)
    f16x2 wh2[16];
#pragma unroll
    for (int m = 0; m < 16; ++m) {
        wh2[m] = (f16x2){ (_Float16)(Wh[(2 * m + 0) * HID + j] * TWO_LOG2E),
                          (_Float16)(Wh[(2 * m + 1) * HID + j] * TWO_LOG2E) };
    }
#pragma unroll
    for (int m = 0; m < 16; ++m) asm("" : "+v"(wh2[m]));  // remat-proof

    h_lds[rA][j] = (_Float16)0.0f;              // h0 = 0, both chains
    h_lds[rB][j] = (_Float16)0.0f;

    const int* xbA = x + bA * TLEN;
    const int* xbB = x + bB * TLEN;

    // pipeline prologue: tokens for quads 0/1, P' for quad 0, both chains
    int4 tqA_cur = *(const int4*)(xbA);
    int4 tqA_nxt = *(const int4*)(xbA + 4);
    int4 tqB_cur = *(const int4*)(xbB);
    int4 tqB_nxt = *(const int4*)(xbB + 4);
    float pa0 = P[tqA_cur.x * HID + j], pb0 = P[tqB_cur.x * HID + j];
    float pa1 = P[tqA_cur.y * HID + j], pb1 = P[tqB_cur.y * HID + j];
    float pa2 = P[tqA_cur.z * HID + j], pb2 = P[tqB_cur.z * HID + j];
    float pa3 = P[tqA_cur.w * HID + j], pb3 = P[tqB_cur.w * HID + j];

    const f16x8* rowA = (const f16x8*)(&h_lds[rA][0]);
    const f16x8* rowB = (const f16x8*)(&h_lds[rB][0]);

    float hjA = 0.0f, hjB = 0.0f;

    // uA = chain A's h row, staged in registers across the skew boundary
    f16x8 uA0 = {}, uA1 = {}, uA2 = {}, uA3 = {};   // h0 = 0

#define PAIR(U, A, B) __builtin_shufflevector((U), (U), (A), (B))
#define DOT16(RES, V0, V1, V2, V3, SEED)                                      \
    float RES;                                                                \
    {                                                                         \
        float a0 = (SEED), a1 = 0.f;                                          \
        a0 = __builtin_amdgcn_fdot2(PAIR(V0,0,1), wh2[0],  a0, false);        \
        a1 = __builtin_amdgcn_fdot2(PAIR(V0,2,3), wh2[1],  a1, false);        \
        a0 = __builtin_amdgcn_fdot2(PAIR(V0,4,5), wh2[2],  a0, false);        \
        a1 = __builtin_amdgcn_fdot2(PAIR(V0,6,7), wh2[3],  a1, false);        \
        a0 = __builtin_amdgcn_fdot2(PAIR(V1,0,1), wh2[4],  a0, false);        \
        a1 = __builtin_amdgcn_fdot2(PAIR(V1,2,3), wh2[5],  a1, false);        \
        a0 = __builtin_amdgcn_fdot2(PAIR(V1,4,5), wh2[6],  a0, false);        \
        a1 = __builtin_amdgcn_fdot2(PAIR(V1,6,7), wh2[7],  a1, false);        \
        a0 = __builtin_amdgcn_fdot2(PAIR(V2,0,1), wh2[8],  a0, false);        \
        a1 = __builtin_amdgcn_fdot2(PAIR(V2,2,3), wh2[9],  a1, false);        \
        a0 = __builtin_amdgcn_fdot2(PAIR(V2,4,5), wh2[10], a0, false);        \
        a1 = __builtin_amdgcn_fdot2(PAIR(V2,6,7), wh2[11], a1, false);        \
        a0 = __builtin_amdgcn_fdot2(PAIR(V3,0,1), wh2[12], a0, false);        \
        a1 = __builtin_amdgcn_fdot2(PAIR(V3,2,3), wh2[13], a1, false);        \
        a0 = __builtin_amdgcn_fdot2(PAIR(V3,4,5), wh2[14], a0, false);        \
        a1 = __builtin_amdgcn_fdot2(PAIR(V3,6,7), wh2[15], a1, false);        \
        RES = a0 + a1;                          /* already x 2log2e */        \
    }
#define TANH_STORE(Z, HJ, ROWIDX)                                             \
    {                                                                         \
        float e2 = __builtin_amdgcn_exp2f(Z);                                 \
        float r  = __builtin_amdgcn_rcpf(e2 + 1.0f);                          \
        HJ = fmaf(-2.0f, r, 1.0f);                                            \
        h_lds[ROWIDX][j] = (_Float16)HJ;                                      \
    }

// One skewed super-step: advances chain A and chain B one timestep each.
// uB load issues first (covered by A's compute); uA reload issues after
// writeA (covered by B's compute) and is consumed next super-step.
#define STEP2(PA, PB)                                                         \
    {                                                                         \
        f16x8 uB0 = rowB[0], uB1 = rowB[1], uB2 = rowB[2], uB3 = rowB[3];     \
        DOT16(zA, uA0, uA1, uA2, uA3, (PA))                                   \
        TANH_STORE(zA, hjA, rA)                                               \
        f16x8 nA0 = rowA[0], nA1 = rowA[1], nA2 = rowA[2], nA3 = rowA[3];     \
        DOT16(zB, uB0, uB1, uB2, uB3, (PB))                                   \
        TANH_STORE(zB, hjB, rB)                                               \
        uA0 = nA0; uA1 = nA1; uA2 = nA2; uA3 = nA3;                           \
    }

    const int NQ = TLEN / 4;                    // 128 quads, exact

    for (int k = 0; k < NQ; ++k) {
        // prefetch P' for quad k+1, both chains (tokens already resident)
        float na0 = P[tqA_nxt.x * HID + j], nb0 = P[tqB_nxt.x * HID + j];
        float na1 = P[tqA_nxt.y * HID + j], nb1 = P[tqB_nxt.y * HID + j];
        float na2 = P[tqA_nxt.z * HID + j], nb2 = P[tqB_nxt.z * HID + j];
        float na3 = P[tqA_nxt.w * HID + j], nb3 = P[tqB_nxt.w * HID + j];
        // prefetch token quads k+2 (clamped; tail values unused)
        int  q2i = (k + 2 < NQ) ? (k + 2) : (NQ - 1);
        int4 tA2 = *(const int4*)(xbA + 4 * q2i);
        int4 tB2 = *(const int4*)(xbB + 4 * q2i);

        STEP2(pa0, pb0)
        STEP2(pa1, pb1)
        STEP2(pa2, pb2)
        STEP2(pa3, pb3)

        pa0 = na0; pa1 = na1; pa2 = na2; pa3 = na3;
        pb0 = nb0; pb1 = nb1; pb2 = nb2; pb3 = nb3;
        tqA_nxt = tA2; tqB_nxt = tB2;
    }
#undef STEP2
#undef TANH_STORE
#undef DOT16
#undef PAIR

    // out[b] = sigmoid(sum_j h_j * Wd[j] + bd) for all 4 batches
    float wd = Wd[j];
    float sA = hjA * wd;
    float sB = hjB * wd;
#pragma unroll
    for (int off = 16; off > 0; off >>= 1) {
        sA += __shfl_xor(sA, off, 32);          // reduce within 32-lane half
        sB += __shfl_xor(sB, off, 32);
    }
    if (j == 0) {
        float bdv = bd[0];
        out[bA] = 1.0f / (1.0f + __expf(-(sA + bdv)));
        out[bB] = 1.0f / (1.0f + __expf(-(sB + bdv)));
    }
}

// ---------------------------------------------------------------------------
extern "C" void kernel_launch(void* const* d_in, const int* in_sizes, int n_in,
                              void* d_out, int out_size, void* d_ws, size_t ws_size,
                              hipStream_t stream)
{
    const int*   x   = (const int*)  d_in[0];
    const float* emb = (const float*)d_in[1];
    const float* Wx  = (const float*)d_in[2];
    const float* Wh  = (const float*)d_in[3];
    const float* bia = (const float*)d_in[4];
    const float* Wd  = (const float*)d_in[5];
    const float* bd  = (const float*)d_in[6];
    float* out = (float*)d_out;

    float* P = (float*)d_ws;                    // VOCAB*HID*4 = 1.28 MB (pre-scaled)

    rnn_proj<<<(VOCAB * HID + 255) / 256, 256, 0, stream>>>(emb, Wx, bia, P);
    rnn_scan<<<BATCH / 16, 256, 0, stream>>>(x, P, Wh, Wd, bd, out);
}

// Round 18
// 85.268 us; speedup vs baseline: 1.4928x; 1.4928x over previous
//
#include <hip/hip_runtime.h>

#define VOCAB 10000
#define EMB   16
#define HID   32
#define BATCH 4096
#define TLEN  512

typedef _Float16 f16x2 __attribute__((ext_vector_type(2)));
typedef _Float16 f16x8 __attribute__((ext_vector_type(8)));

#define TWO_LOG2E 2.8853900817779268f   /* 2*log2(e) */

// ---------------------------------------------------------------------------
// Kernel 1: P'[v][j] = (b[j] + sum_e emb[v][e]*Wx[e][j]) * 2log2e
// ---------------------------------------------------------------------------
__global__ __launch_bounds__(256) void rnn_proj(
    const float* __restrict__ emb, const float* __restrict__ Wx,
    const float* __restrict__ bias, float* __restrict__ P)
{
    int tid = blockIdx.x * 256 + threadIdx.x;
    if (tid >= VOCAB * HID) return;
    int v = tid >> 5;
    int j = tid & 31;
    float acc = bias[j];
    const float* ev = emb + v * EMB;
#pragma unroll
    for (int e = 0; e < EMB; ++e) {
        acc = fmaf(ev[e], Wx[e * HID + j], acc);
    }
    P[tid] = acc * TWO_LOG2E;
}

// ---------------------------------------------------------------------------
// Kernel 2: fp16/fdot2 scan (r16 structure — proven best at 86us/dispatch)
// + phase stagger. r16's remaining 40% stall: the 2 co-resident waves per
// SIMD run identical-length loops and hit the ~120cy LDS write->read
// round-trip IN PHASE, so neither covers the other's stall. One-time
// s_sleep(2) (~128cy =~ half a step) before the loop for half the blocks
// anti-phases co-resident pairs; identical loop lengths preserve the
// offset for all 512 iterations. Stagger parity (bid ^ bid>>8) & 1 covers
// both plausible co-residency pairings ((2i,2i+1) and (i,i+256)).
// Everything else identical to r16: 2log2e fold (exp2 direct), 16 fdot2
// with 2 accumulators, f16 h rows (4 ds_read_b128), quad unroll, int4
// tokens, P prefetch one quad ahead, pinned weights, waves_per_eu(2,2).
// ---------------------------------------------------------------------------
__global__ __launch_bounds__(256)
__attribute__((amdgpu_waves_per_eu(2, 2)))
void rnn_scan(
    const int*   __restrict__ x,   const float* __restrict__ P,
    const float* __restrict__ Wh,  const float* __restrict__ Wd,
    const float* __restrict__ bd,  float* __restrict__ out)
{
    __shared__ _Float16 h_lds[8][HID];          // 8 rows x 64 B

    const int lane = threadIdx.x & 63;
    const int wave = threadIdx.x >> 6;
    const int half = lane >> 5;
    const int j    = lane & 31;
    const int hb   = wave * 2 + half;           // wave-private row
    const int b    = blockIdx.x * 8 + hb;

    // Wh column j, pre-scaled by 2log2e, as fp16 pairs
    f16x2 wh2[16];
#pragma unroll
    for (int m = 0; m < 16; ++m) {
        wh2[m] = (f16x2){ (_Float16)(Wh[(2 * m + 0) * HID + j] * TWO_LOG2E),
                          (_Float16)(Wh[(2 * m + 1) * HID + j] * TWO_LOG2E) };
    }
#pragma unroll
    for (int m = 0; m < 16; ++m) asm("" : "+v"(wh2[m]));  // remat-proof

    h_lds[hb][j] = (_Float16)0.0f;              // h0 = 0 (wave-private)

    const int* xb = x + b * TLEN;

    // pipeline prologue: tokens for quads 0/1, P' for quad 0
    int4 tq_cur = *(const int4*)(xb);
    int4 tq_nxt = *(const int4*)(xb + 4);
    float pc0 = P[tq_cur.x * HID + j];
    float pc1 = P[tq_cur.y * HID + j];
    float pc2 = P[tq_cur.z * HID + j];
    float pc3 = P[tq_cur.w * HID + j];

    float hj = 0.0f;
    const f16x8* hrow = (const f16x8*)(&h_lds[hb][0]);

    // ---- phase stagger: anti-phase co-resident waves (see header) ----
    if ((blockIdx.x ^ (blockIdx.x >> 8)) & 1)
        __builtin_amdgcn_s_sleep(2);            // ~128 cy, once

#define PAIR(U, A, B) __builtin_shufflevector((U), (U), (A), (B))
#define STEP(PV)                                                              \
    {                                                                         \
        f16x8 u0 = hrow[0], u1 = hrow[1], u2 = hrow[2], u3 = hrow[3];         \
        float a0 = (PV), a1 = 0.f;                                            \
        a0 = __builtin_amdgcn_fdot2(PAIR(u0,0,1), wh2[0],  a0, false);        \
        a1 = __builtin_amdgcn_fdot2(PAIR(u0,2,3), wh2[1],  a1, false);        \
        a0 = __builtin_amdgcn_fdot2(PAIR(u0,4,5), wh2[2],  a0, false);        \
        a1 = __builtin_amdgcn_fdot2(PAIR(u0,6,7), wh2[3],  a1, false);        \
        a0 = __builtin_amdgcn_fdot2(PAIR(u1,0,1), wh2[4],  a0, false);        \
        a1 = __builtin_amdgcn_fdot2(PAIR(u1,2,3), wh2[5],  a1, false);        \
        a0 = __builtin_amdgcn_fdot2(PAIR(u1,4,5), wh2[6],  a0, false);        \
        a1 = __builtin_amdgcn_fdot2(PAIR(u1,6,7), wh2[7],  a1, false);        \
        a0 = __builtin_amdgcn_fdot2(PAIR(u2,0,1), wh2[8],  a0, false);        \
        a1 = __builtin_amdgcn_fdot2(PAIR(u2,2,3), wh2[9],  a1, false);        \
        a0 = __builtin_amdgcn_fdot2(PAIR(u2,4,5), wh2[10], a0, false);        \
        a1 = __builtin_amdgcn_fdot2(PAIR(u2,6,7), wh2[11], a1, false);        \
        a0 = __builtin_amdgcn_fdot2(PAIR(u3,0,1), wh2[12], a0, false);        \
        a1 = __builtin_amdgcn_fdot2(PAIR(u3,2,3), wh2[13], a1, false);        \
        a0 = __builtin_amdgcn_fdot2(PAIR(u3,4,5), wh2[14], a0, false);        \
        a1 = __builtin_amdgcn_fdot2(PAIR(u3,6,7), wh2[15], a1, false);        \
        float z  = a0 + a1;                     /* already x 2log2e */        \
        float e2 = __builtin_amdgcn_exp2f(z);   /* = e^{2z_true} */           \
        float r  = __builtin_amdgcn_rcpf(e2 + 1.0f);                          \
        hj = fmaf(-2.0f, r, 1.0f);                                            \
        h_lds[hb][j] = (_Float16)hj;                                          \
    }

    const int NQ = TLEN / 4;                    // 128 quads, exact

    for (int k = 0; k < NQ; ++k) {
        // prefetch P' for quad k+1 (tokens already resident in tq_nxt)
        float pn0 = P[tq_nxt.x * HID + j];
        float pn1 = P[tq_nxt.y * HID + j];
        float pn2 = P[tq_nxt.z * HID + j];
        float pn3 = P[tq_nxt.w * HID + j];
        // prefetch token quad k+2 (clamped; tail values unused)
        int  q2i = (k + 2 < NQ) ? (k + 2) : (NQ - 1);
        int4 tq2 = *(const int4*)(xb + 4 * q2i);

        STEP(pc0)
        STEP(pc1)
        STEP(pc2)
        STEP(pc3)

        pc0 = pn0; pc1 = pn1; pc2 = pn2; pc3 = pn3;
        tq_nxt = tq2;
    }
#undef STEP
#undef PAIR

    // out[b] = sigmoid(sum_j h_j * Wd[j] + bd)
    float s = hj * Wd[j];
#pragma unroll
    for (int off = 16; off > 0; off >>= 1)
        s += __shfl_xor(s, off, 32);            // reduce within 32-lane half
    if (j == 0) {
        float logit = s + bd[0];
        out[b] = 1.0f / (1.0f + __expf(-logit)); // fp32 output
    }
}

// ---------------------------------------------------------------------------
extern "C" void kernel_launch(void* const* d_in, const int* in_sizes, int n_in,
                              void* d_out, int out_size, void* d_ws, size_t ws_size,
                              hipStream_t stream)
{
    const int*   x   = (const int*)  d_in[0];
    const float* emb = (const float*)d_in[1];
    const float* Wx  = (const float*)d_in[2];
    const float* Wh  = (const float*)d_in[3];
    const float* bia = (const float*)d_in[4];
    const float* Wd  = (const float*)d_in[5];
    const float* bd  = (const float*)d_in[6];
    float* out = (float*)d_out;

    float* P = (float*)d_ws;                    // VOCAB*HID*4 = 1.28 MB (pre-scaled)

    rnn_proj<<<(VOCAB * HID + 255) / 256, 256, 0, stream>>>(emb, Wx, bia, P);
    rnn_scan<<<BATCH / 8, 256, 0, stream>>>(x, P, Wh, Wd, bd, out);
}